// Round 1
// baseline (861.880 us; speedup 1.0000x reference)
//
#include <hip/hip_runtime.h>
#include <math.h>

// GAT encoder: N=10000 nodes, E=160000 edges (+N self loops), H=8 heads, C=128, D=1024.
// All fp32. CSR-by-dst built on device once per launch; logits stored in dst-sorted
// order so softmax/aggregation is fully coalesced and atomic-free.

#define THREADS 256

__device__ __forceinline__ float gelu_exact(float x) {
  return 0.5f * x * (1.0f + erff(x * 0.70710678118654752f));
}

// ---------------- CSR build ----------------

__global__ void hist_kernel(const int* __restrict__ ei, int E, int ET, int* __restrict__ counts) {
  int e = blockIdx.x * THREADS + threadIdx.x;
  if (e >= ET) return;
  int d = (e < E) ? ei[E + e] : (e - E);
  atomicAdd(&counts[d], 1);
}

__global__ __launch_bounds__(1024) void scan_kernel(const int* __restrict__ counts,
                                                    int* __restrict__ offsets,
                                                    int* __restrict__ cursor, int n) {
  __shared__ int sums[1024];
  int t = threadIdx.x;
  int per = (n + 1023) >> 10;
  int start = t * per; if (start > n) start = n;
  int end = start + per; if (end > n) end = n;
  int local = 0;
  for (int i = start; i < end; ++i) local += counts[i];
  sums[t] = local;
  __syncthreads();
  for (int off = 1; off < 1024; off <<= 1) {
    int add = (t >= off) ? sums[t - off] : 0;
    __syncthreads();
    sums[t] += add;
    __syncthreads();
  }
  int run = (t == 0) ? 0 : sums[t - 1];
  for (int i = start; i < end; ++i) {
    offsets[i] = run; cursor[i] = run; run += counts[i];
  }
  if (t == 1023) offsets[n] = run;
}

__global__ void scatter_kernel(const int* __restrict__ ei, int E, int ET,
                               int* __restrict__ cursor, int* __restrict__ pos_of,
                               int* __restrict__ srcs) {
  int e = blockIdx.x * THREADS + threadIdx.x;
  if (e >= ET) return;
  int s = (e < E) ? ei[e] : (e - E);
  int d = (e < E) ? ei[E + e] : (e - E);
  int pos = atomicAdd(&cursor[d], 1);
  pos_of[e] = pos;
  srcs[pos] = s;
}

// ---------------- layer 1 feature transform (K=4) ----------------

__global__ void feat1_kernel(const float* __restrict__ x, const float* __restrict__ w,
                             float* __restrict__ out, int total) {
  int idx = blockIdx.x * THREADS + threadIdx.x;
  if (idx >= total) return;
  int n = idx >> 10, d = idx & 1023;
  float4 xv = *(const float4*)&x[n * 4];
  out[idx] = xv.x * w[d] + xv.y * w[1024 + d] + xv.z * w[2048 + d] + xv.w * w[3072 + d];
}

// ---------------- A[N,128] @ W[128,1024] -> C[N,1024] ----------------
// 64x64 tile, full K=128 in LDS (A stored k-major/transposed for float4 reads).

__global__ __launch_bounds__(256) void gemm128_kernel(const float* __restrict__ A,
                                                      const float* __restrict__ W,
                                                      float* __restrict__ C, int N) {
  __shared__ float AsT[128][64];  // [k][row]
  __shared__ float Ws[128][64];   // [k][col]
  int t = threadIdx.x;
  int n0 = blockIdx.y * 64;
  int d0 = blockIdx.x * 64;
  for (int i = t; i < 2048; i += 256) {
    int row = i >> 5;
    int col4 = (i & 31) << 2;
    int n = n0 + row;
    float4 v = make_float4(0.f, 0.f, 0.f, 0.f);
    if (n < N) v = *(const float4*)&A[(size_t)n * 128 + col4];
    AsT[col4 + 0][row] = v.x; AsT[col4 + 1][row] = v.y;
    AsT[col4 + 2][row] = v.z; AsT[col4 + 3][row] = v.w;
  }
  for (int i = t; i < 2048; i += 256) {
    int k = i >> 4;
    int c4 = (i & 15) << 2;
    *(float4*)&Ws[k][c4] = *(const float4*)&W[(size_t)k * 1024 + d0 + c4];
  }
  __syncthreads();
  int tx = t & 15, ty = t >> 4;
  float acc[4][4] = {};
#pragma unroll 4
  for (int k = 0; k < 128; ++k) {
    float4 a = *(float4*)&AsT[k][ty * 4];
    float4 w = *(float4*)&Ws[k][tx * 4];
    acc[0][0] += a.x * w.x; acc[0][1] += a.x * w.y; acc[0][2] += a.x * w.z; acc[0][3] += a.x * w.w;
    acc[1][0] += a.y * w.x; acc[1][1] += a.y * w.y; acc[1][2] += a.y * w.z; acc[1][3] += a.y * w.w;
    acc[2][0] += a.z * w.x; acc[2][1] += a.z * w.y; acc[2][2] += a.z * w.z; acc[2][3] += a.z * w.w;
    acc[3][0] += a.w * w.x; acc[3][1] += a.w * w.y; acc[3][2] += a.w * w.z; acc[3][3] += a.w * w.w;
  }
#pragma unroll
  for (int i = 0; i < 4; ++i) {
    int n = n0 + ty * 4 + i;
    if (n < N) {
      float4 o = make_float4(acc[i][0], acc[i][1], acc[i][2], acc[i][3]);
      *(float4*)&C[(size_t)n * 1024 + d0 + tx * 4] = o;
    }
  }
}

// ---------------- per-node head scores ----------------

__global__ __launch_bounds__(256) void scores_kernel(const float* __restrict__ H,
                                                     const float* __restrict__ as,
                                                     const float* __restrict__ ad,
                                                     float* __restrict__ ssrc,
                                                     float* __restrict__ sdst, int N) {
  int n = blockIdx.x;
  int t = threadIdx.x;
  int head = t >> 5, lane = t & 31;
  const float* hp = H + (size_t)n * 1024 + head * 128 + lane * 4;
  float4 h4 = *(const float4*)hp;
  float4 a4 = *(const float4*)&as[head * 128 + lane * 4];
  float4 d4 = *(const float4*)&ad[head * 128 + lane * 4];
  float s1 = h4.x * a4.x + h4.y * a4.y + h4.z * a4.z + h4.w * a4.w;
  float s2 = h4.x * d4.x + h4.y * d4.y + h4.z * d4.z + h4.w * d4.w;
  for (int off = 16; off; off >>= 1) {
    s1 += __shfl_down(s1, off, 32);
    s2 += __shfl_down(s2, off, 32);
  }
  if (lane == 0) { ssrc[n * 8 + head] = s1; sdst[n * 8 + head] = s2; }
}

// ---------------- per-edge logits, written in dst-sorted order ----------------

__global__ void elog_kernel(const int* __restrict__ ei, int E, int ET,
                            const float* __restrict__ ssrc, const float* __restrict__ sdst,
                            const int* __restrict__ pos_of, float* __restrict__ elog) {
  int i = blockIdx.x * THREADS + threadIdx.x;
  if (i >= ET * 8) return;
  int e = i >> 3, h = i & 7;
  int s = (e < E) ? ei[e] : (e - E);
  int d = (e < E) ? ei[E + e] : (e - E);
  float v = ssrc[s * 8 + h] + sdst[d * 8 + h];
  v = (v > 0.f) ? v : 0.2f * v;
  elog[(size_t)pos_of[e] * 8 + h] = v;
}

// ---------------- softmax + weighted aggregation (one block per dst node) ----------------

__global__ __launch_bounds__(256) void agg_kernel(const float* __restrict__ H,
                                                  const float* __restrict__ elog,
                                                  const int* __restrict__ offsets,
                                                  const int* __restrict__ srcs,
                                                  const float* __restrict__ bias,
                                                  float* __restrict__ out, int N) {
  int n = blockIdx.x;
  int t = threadIdx.x;
  int head = t >> 5, lane = t & 31;
  int start = offsets[n], end = offsets[n + 1];
  int deg = end - start;
  __shared__ float sm[8], sz[8];
  // phase 1: online softmax stats per head across incoming edges
  float m = -1e30f, s = 0.f;
  for (int i = lane; i < deg; i += 32) {
    float v = elog[(size_t)(start + i) * 8 + head];
    if (v > m) { s = s * __expf(m - v) + 1.f; m = v; }
    else s += __expf(v - m);
  }
  for (int off = 16; off; off >>= 1) {
    float m2 = __shfl_down(m, off, 32);
    float s2 = __shfl_down(s, off, 32);
    float M = fmaxf(m, m2);
    s = s * __expf(m - M) + s2 * __expf(m2 - M);
    m = M;
  }
  if (lane == 0) { sm[head] = m; sz[head] = 1.f / s; }
  __syncthreads();
  float mh = sm[head], zinv = sz[head];
  // phase 2: out[n, 4t..4t+3] = sum_e alpha * H[src, 4t..4t+3] + bias
  float4 acc = make_float4(0.f, 0.f, 0.f, 0.f);
  int coff = t * 4;
  for (int i = 0; i < deg; ++i) {
    int sp = srcs[start + i];
    float a = __expf(elog[(size_t)(start + i) * 8 + head] - mh) * zinv;
    float4 hv = *(const float4*)&H[(size_t)sp * 1024 + coff];
    acc.x += a * hv.x; acc.y += a * hv.y; acc.z += a * hv.z; acc.w += a * hv.w;
  }
  float4 b4 = *(const float4*)&bias[coff];
  acc.x += b4.x; acc.y += b4.y; acc.z += b4.z; acc.w += b4.w;
  *(float4*)&out[(size_t)n * 1024 + coff] = acc;
}

// ---------------- gelu(B[N,1024]) @ W[1024,128] + bias -> C[N,128] ----------------

__global__ __launch_bounds__(256) void proj_kernel(const float* __restrict__ Bm,
                                                   const float* __restrict__ W,
                                                   const float* __restrict__ bias,
                                                   float* __restrict__ C, int N) {
  __shared__ float As[32][68];   // 32 rows x 64 k-chunk (pad 68 keeps float4 alignment)
  __shared__ float Ws[64][128];
  int t = threadIdx.x;
  int n0 = blockIdx.x * 32;
  int tx = t & 31, ty = t >> 5;
  float acc[4][4] = {};
  for (int kc = 0; kc < 1024; kc += 64) {
    for (int i = t; i < 512; i += 256) {
      int row = i >> 4, col4 = (i & 15) << 2;
      int n = n0 + row;
      float4 v = make_float4(0.f, 0.f, 0.f, 0.f);
      if (n < N) v = *(const float4*)&Bm[(size_t)n * 1024 + kc + col4];
      v.x = gelu_exact(v.x); v.y = gelu_exact(v.y);
      v.z = gelu_exact(v.z); v.w = gelu_exact(v.w);
      *(float4*)&As[row][col4] = v;
    }
    for (int i = t; i < 2048; i += 256) {
      int k = i >> 5, c4 = (i & 31) << 2;
      *(float4*)&Ws[k][c4] = *(const float4*)&W[(size_t)(kc + k) * 128 + c4];
    }
    __syncthreads();
#pragma unroll 4
    for (int k = 0; k < 64; ++k) {
      float a[4];
#pragma unroll
      for (int i = 0; i < 4; ++i) a[i] = As[ty * 4 + i][k];
      float4 w = *(float4*)&Ws[k][tx * 4];
#pragma unroll
      for (int i = 0; i < 4; ++i) {
        acc[i][0] += a[i] * w.x; acc[i][1] += a[i] * w.y;
        acc[i][2] += a[i] * w.z; acc[i][3] += a[i] * w.w;
      }
    }
    __syncthreads();
  }
  float4 b4 = *(const float4*)&bias[tx * 4];
#pragma unroll
  for (int i = 0; i < 4; ++i) {
    int n = n0 + ty * 4 + i;
    if (n < N) {
      float4 o = make_float4(acc[i][0] + b4.x, acc[i][1] + b4.y,
                             acc[i][2] + b4.z, acc[i][3] + b4.w);
      *(float4*)&C[(size_t)n * 128 + tx * 4] = o;
    }
  }
}

// ---------------- orchestration ----------------

extern "C" void kernel_launch(void* const* d_in, const int* in_sizes, int n_in,
                              void* d_out, int out_size, void* d_ws, size_t ws_size,
                              hipStream_t stream) {
  const float* x   = (const float*)d_in[0];
  const int*   ei  = (const int*)d_in[1];
  const float* w1  = (const float*)d_in[2];
  const float* as1 = (const float*)d_in[3];
  const float* ad1 = (const float*)d_in[4];
  const float* b1  = (const float*)d_in[5];
  const float* w2  = (const float*)d_in[6];
  const float* as2 = (const float*)d_in[7];
  const float* ad2 = (const float*)d_in[8];
  const float* b2  = (const float*)d_in[9];
  const float* w3  = (const float*)d_in[10];
  const float* as3 = (const float*)d_in[11];
  const float* ad3 = (const float*)d_in[12];
  const float* b3  = (const float*)d_in[13];
  const float* rw1 = (const float*)d_in[14];
  const float* rb1 = (const float*)d_in[15];
  const float* rw2 = (const float*)d_in[16];
  const float* rb2 = (const float*)d_in[17];
  const float* lw  = (const float*)d_in[18];
  const float* lb  = (const float*)d_in[19];

  int N = in_sizes[0] / 4;
  int E = in_sizes[1] / 2;
  int ET = E + N;

  char* wsb = (char*)d_ws;
  size_t off = 0;
  auto alloc = [&](size_t bytes) -> void* {
    void* p = wsb + off;
    off += (bytes + 255) & ~(size_t)255;
    return p;
  };
  float* A    = (float*)alloc((size_t)N * 1024 * 4);  // transformed features h
  float* Bf   = (float*)alloc((size_t)N * 1024 * 4);  // GAT output
  float* P    = (float*)alloc((size_t)N * 128 * 4);   // projected features
  float* ssrc = (float*)alloc((size_t)N * 8 * 4);
  float* sdst = (float*)alloc((size_t)N * 8 * 4);
  float* elog = (float*)alloc((size_t)ET * 8 * 4);
  int* counts  = (int*)alloc((size_t)N * 4);
  int* offsets = (int*)alloc((size_t)(N + 1) * 4);
  int* cursor  = (int*)alloc((size_t)N * 4);
  int* pos_of  = (int*)alloc((size_t)ET * 4);
  int* srcs    = (int*)alloc((size_t)ET * 4);

  // CSR build (graph identical for all 3 layers)
  hipMemsetAsync(counts, 0, (size_t)N * 4, stream);
  hist_kernel<<<dim3((ET + THREADS - 1) / THREADS), dim3(THREADS), 0, stream>>>(ei, E, ET, counts);
  scan_kernel<<<dim3(1), dim3(1024), 0, stream>>>(counts, offsets, cursor, N);
  scatter_kernel<<<dim3((ET + THREADS - 1) / THREADS), dim3(THREADS), 0, stream>>>(ei, E, ET, cursor, pos_of, srcs);

  dim3 gEdgeH((ET * 8 + THREADS - 1) / THREADS);
  dim3 gNode(N);
  dim3 gGemm(16, (N + 63) / 64);
  dim3 gProj((N + 31) / 32);
  dim3 blk(THREADS);

  // ---- layer 1 ----
  feat1_kernel<<<dim3((N * 1024 + THREADS - 1) / THREADS), blk, 0, stream>>>(x, w1, A, N * 1024);
  scores_kernel<<<gNode, blk, 0, stream>>>(A, as1, ad1, ssrc, sdst, N);
  elog_kernel<<<gEdgeH, blk, 0, stream>>>(ei, E, ET, ssrc, sdst, pos_of, elog);
  agg_kernel<<<gNode, blk, 0, stream>>>(A, elog, offsets, srcs, b1, Bf, N);
  proj_kernel<<<gProj, blk, 0, stream>>>(Bf, rw1, rb1, P, N);

  // ---- layer 2 ----
  gemm128_kernel<<<gGemm, blk, 0, stream>>>(P, w2, A, N);
  scores_kernel<<<gNode, blk, 0, stream>>>(A, as2, ad2, ssrc, sdst, N);
  elog_kernel<<<gEdgeH, blk, 0, stream>>>(ei, E, ET, ssrc, sdst, pos_of, elog);
  agg_kernel<<<gNode, blk, 0, stream>>>(A, elog, offsets, srcs, b2, Bf, N);
  proj_kernel<<<gProj, blk, 0, stream>>>(Bf, rw2, rb2, P, N);

  // ---- layer 3 ----
  gemm128_kernel<<<gGemm, blk, 0, stream>>>(P, w3, A, N);
  scores_kernel<<<gNode, blk, 0, stream>>>(A, as3, ad3, ssrc, sdst, N);
  elog_kernel<<<gEdgeH, blk, 0, stream>>>(ei, E, ET, ssrc, sdst, pos_of, elog);
  agg_kernel<<<gNode, blk, 0, stream>>>(A, elog, offsets, srcs, b3, Bf, N);
  proj_kernel<<<gProj, blk, 0, stream>>>(Bf, lw, lb, (float*)d_out, N);
}

// Round 2
// 799.704 us; speedup vs baseline: 1.0777x; 1.0777x over previous
//
#include <hip/hip_runtime.h>
#include <math.h>

// GAT encoder: N=10000 nodes, E=160000 edges (+N self loops), H=8 heads, C=128, D=1024.
// All fp32. CSR-by-dst built on device once per launch; logits stored in dst-sorted
// order so softmax/aggregation is fully coalesced and atomic-free.

#define THREADS 256

__device__ __forceinline__ float gelu_exact(float x) {
  return 0.5f * x * (1.0f + erff(x * 0.70710678118654752f));
}

// ---------------- CSR build ----------------

__global__ void hist_kernel(const int* __restrict__ ei, int E, int ET, int* __restrict__ counts) {
  int e = blockIdx.x * THREADS + threadIdx.x;
  if (e >= ET) return;
  int d = (e < E) ? ei[E + e] : (e - E);
  atomicAdd(&counts[d], 1);
}

__global__ __launch_bounds__(1024) void scan_kernel(const int* __restrict__ counts,
                                                    int* __restrict__ offsets,
                                                    int* __restrict__ cursor, int n) {
  __shared__ int sums[1024];
  int t = threadIdx.x;
  int per = (n + 1023) >> 10;
  int start = t * per; if (start > n) start = n;
  int end = start + per; if (end > n) end = n;
  int local = 0;
  for (int i = start; i < end; ++i) local += counts[i];
  sums[t] = local;
  __syncthreads();
  for (int off = 1; off < 1024; off <<= 1) {
    int add = (t >= off) ? sums[t - off] : 0;
    __syncthreads();
    sums[t] += add;
    __syncthreads();
  }
  int run = (t == 0) ? 0 : sums[t - 1];
  for (int i = start; i < end; ++i) {
    offsets[i] = run; cursor[i] = run; run += counts[i];
  }
  if (t == 1023) offsets[n] = run;
}

__global__ void scatter_kernel(const int* __restrict__ ei, int E, int ET,
                               int* __restrict__ cursor, int* __restrict__ pos_of,
                               int* __restrict__ srcs) {
  int e = blockIdx.x * THREADS + threadIdx.x;
  if (e >= ET) return;
  int s = (e < E) ? ei[e] : (e - E);
  int d = (e < E) ? ei[E + e] : (e - E);
  int pos = atomicAdd(&cursor[d], 1);
  pos_of[e] = pos;
  srcs[pos] = s;
}

// ---------------- layer 1 feature transform (K=4) ----------------

__global__ void feat1_kernel(const float* __restrict__ x, const float* __restrict__ w,
                             float* __restrict__ out, int total) {
  int idx = blockIdx.x * THREADS + threadIdx.x;
  if (idx >= total) return;
  int n = idx >> 10, d = idx & 1023;
  float4 xv = *(const float4*)&x[n * 4];
  out[idx] = xv.x * w[d] + xv.y * w[1024 + d] + xv.z * w[2048 + d] + xv.w * w[3072 + d];
}

// ---------------- A[N,128] @ W[128,1024] -> C[N,1024] ----------------
// 64x64 tile, full K=128 in LDS (A stored k-major/transposed for float4 reads).

__global__ __launch_bounds__(256) void gemm128_kernel(const float* __restrict__ A,
                                                      const float* __restrict__ W,
                                                      float* __restrict__ C, int N) {
  __shared__ float AsT[128][64];  // [k][row]
  __shared__ float Ws[128][64];   // [k][col]
  int t = threadIdx.x;
  int n0 = blockIdx.y * 64;
  int d0 = blockIdx.x * 64;
  for (int i = t; i < 2048; i += 256) {
    int row = i >> 5;
    int col4 = (i & 31) << 2;
    int n = n0 + row;
    float4 v = make_float4(0.f, 0.f, 0.f, 0.f);
    if (n < N) v = *(const float4*)&A[(size_t)n * 128 + col4];
    AsT[col4 + 0][row] = v.x; AsT[col4 + 1][row] = v.y;
    AsT[col4 + 2][row] = v.z; AsT[col4 + 3][row] = v.w;
  }
  for (int i = t; i < 2048; i += 256) {
    int k = i >> 4;
    int c4 = (i & 15) << 2;
    *(float4*)&Ws[k][c4] = *(const float4*)&W[(size_t)k * 1024 + d0 + c4];
  }
  __syncthreads();
  int tx = t & 15, ty = t >> 4;
  float acc[4][4] = {};
#pragma unroll 4
  for (int k = 0; k < 128; ++k) {
    float4 a = *(float4*)&AsT[k][ty * 4];
    float4 w = *(float4*)&Ws[k][tx * 4];
    acc[0][0] += a.x * w.x; acc[0][1] += a.x * w.y; acc[0][2] += a.x * w.z; acc[0][3] += a.x * w.w;
    acc[1][0] += a.y * w.x; acc[1][1] += a.y * w.y; acc[1][2] += a.y * w.z; acc[1][3] += a.y * w.w;
    acc[2][0] += a.z * w.x; acc[2][1] += a.z * w.y; acc[2][2] += a.z * w.z; acc[2][3] += a.z * w.w;
    acc[3][0] += a.w * w.x; acc[3][1] += a.w * w.y; acc[3][2] += a.w * w.z; acc[3][3] += a.w * w.w;
  }
#pragma unroll
  for (int i = 0; i < 4; ++i) {
    int n = n0 + ty * 4 + i;
    if (n < N) {
      float4 o = make_float4(acc[i][0], acc[i][1], acc[i][2], acc[i][3]);
      *(float4*)&C[(size_t)n * 1024 + d0 + tx * 4] = o;
    }
  }
}

// ---------------- per-node head scores ----------------

__global__ __launch_bounds__(256) void scores_kernel(const float* __restrict__ H,
                                                     const float* __restrict__ as,
                                                     const float* __restrict__ ad,
                                                     float* __restrict__ ssrc,
                                                     float* __restrict__ sdst, int N) {
  int n = blockIdx.x;
  int t = threadIdx.x;
  int head = t >> 5, lane = t & 31;
  const float* hp = H + (size_t)n * 1024 + head * 128 + lane * 4;
  float4 h4 = *(const float4*)hp;
  float4 a4 = *(const float4*)&as[head * 128 + lane * 4];
  float4 d4 = *(const float4*)&ad[head * 128 + lane * 4];
  float s1 = h4.x * a4.x + h4.y * a4.y + h4.z * a4.z + h4.w * a4.w;
  float s2 = h4.x * d4.x + h4.y * d4.y + h4.z * d4.z + h4.w * d4.w;
  for (int off = 16; off; off >>= 1) {
    s1 += __shfl_down(s1, off, 32);
    s2 += __shfl_down(s2, off, 32);
  }
  if (lane == 0) { ssrc[n * 8 + head] = s1; sdst[n * 8 + head] = s2; }
}

// ---------------- per-edge logits, written in dst-sorted order ----------------

__global__ void elog_kernel(const int* __restrict__ ei, int E, int ET,
                            const float* __restrict__ ssrc, const float* __restrict__ sdst,
                            const int* __restrict__ pos_of, float* __restrict__ elog) {
  int i = blockIdx.x * THREADS + threadIdx.x;
  if (i >= ET * 8) return;
  int e = i >> 3, h = i & 7;
  int s = (e < E) ? ei[e] : (e - E);
  int d = (e < E) ? ei[E + e] : (e - E);
  float v = ssrc[s * 8 + h] + sdst[d * 8 + h];
  v = (v > 0.f) ? v : 0.2f * v;
  elog[(size_t)pos_of[e] * 8 + h] = v;
}

// ---------------- softmax + weighted aggregation (one block per dst node) ----------------
// Phase 1: online softmax stats (m, z) per head.
// Phase 2: 64-edge chunks; src indices + exp(v-m) numerators staged in LDS,
//          8-way unrolled gather so 8 float4 loads are in flight per thread.

__global__ __launch_bounds__(256) void agg_kernel(const float* __restrict__ H,
                                                  const float* __restrict__ elog,
                                                  const int* __restrict__ offsets,
                                                  const int* __restrict__ srcs,
                                                  const float* __restrict__ bias,
                                                  float* __restrict__ out, int N) {
  int n = blockIdx.x;
  int t = threadIdx.x;
  int head = t >> 5, lane = t & 31;
  int start = offsets[n];
  int deg = offsets[n + 1] - start;
  __shared__ float sm[8], sz[8];
  __shared__ int ls[64];
  __shared__ float lal[64 * 8];

  // phase 1: online softmax stats per head
  float m = -1e30f, s = 0.f;
  for (int i = lane; i < deg; i += 32) {
    float v = elog[(size_t)(start + i) * 8 + head];
    if (v > m) { s = s * __expf(m - v) + 1.f; m = v; }
    else s += __expf(v - m);
  }
  for (int off = 16; off; off >>= 1) {
    float m2 = __shfl_down(m, off, 32);
    float s2 = __shfl_down(s, off, 32);
    float M = fmaxf(m, m2);
    s = s * __expf(m - M) + s2 * __expf(m2 - M);
    m = M;
  }
  if (lane == 0) { sm[head] = m; sz[head] = 1.f / s; }
  __syncthreads();

  int coff = t * 4;
  float4 acc = make_float4(0.f, 0.f, 0.f, 0.f);
  for (int c0 = 0; c0 < deg; c0 += 64) {
    int cm = min(64, deg - c0);
    if (t < cm) ls[t] = srcs[start + c0 + t];
    for (int j = t; j < cm * 8; j += 256) {
      int e = j >> 3, h = j & 7;
      lal[j] = __expf(elog[(size_t)(start + c0 + e) * 8 + h] - sm[h]);
    }
    __syncthreads();
    int i = 0;
    for (; i + 8 <= cm; i += 8) {
      float4 hv[8]; float av[8];
#pragma unroll
      for (int u = 0; u < 8; ++u) {
        hv[u] = *(const float4*)&H[(size_t)ls[i + u] * 1024 + coff];
        av[u] = lal[(i + u) * 8 + head];
      }
#pragma unroll
      for (int u = 0; u < 8; ++u) {
        acc.x += av[u] * hv[u].x; acc.y += av[u] * hv[u].y;
        acc.z += av[u] * hv[u].z; acc.w += av[u] * hv[u].w;
      }
    }
    for (; i < cm; ++i) {
      float a = lal[i * 8 + head];
      float4 hv = *(const float4*)&H[(size_t)ls[i] * 1024 + coff];
      acc.x += a * hv.x; acc.y += a * hv.y; acc.z += a * hv.z; acc.w += a * hv.w;
    }
    __syncthreads();
  }
  float zinv = sz[head];
  float4 b4 = *(const float4*)&bias[coff];
  acc.x = acc.x * zinv + b4.x; acc.y = acc.y * zinv + b4.y;
  acc.z = acc.z * zinv + b4.z; acc.w = acc.w * zinv + b4.w;
  *(float4*)&out[(size_t)n * 1024 + coff] = acc;
}

// ---------------- gelu(B[N,1024]) @ W[1024,128] + bias -> C[N,128] ----------------
// 16-row x 128-col tile per block (625 blocks), 64-k chunks. LDS 36 KB -> 4 blocks/CU.

__global__ __launch_bounds__(256) void proj_kernel(const float* __restrict__ Bm,
                                                   const float* __restrict__ W,
                                                   const float* __restrict__ bias,
                                                   float* __restrict__ C, int N) {
  __shared__ float As[16][64];
  __shared__ float Ws[64][128];
  int t = threadIdx.x;
  int n0 = blockIdx.x * 16;
  int tx = t & 31, ty = t >> 5;  // tx: col4 group (32 x 4 = 128 cols), ty: row pair (8 x 2 = 16 rows)
  float acc[2][4] = {};
  for (int kc = 0; kc < 1024; kc += 64) {
    {
      int row = t >> 4, col4 = (t & 15) << 2;
      int n = n0 + row;
      float4 v = make_float4(0.f, 0.f, 0.f, 0.f);
      if (n < N) v = *(const float4*)&Bm[(size_t)n * 1024 + kc + col4];
      v.x = gelu_exact(v.x); v.y = gelu_exact(v.y);
      v.z = gelu_exact(v.z); v.w = gelu_exact(v.w);
      *(float4*)&As[row][col4] = v;
    }
#pragma unroll
    for (int u = 0; u < 8; ++u) {
      int j = t + u * 256;
      int k = j >> 5, c4 = (j & 31) << 2;
      *(float4*)&Ws[k][c4] = *(const float4*)&W[(size_t)(kc + k) * 128 + c4];
    }
    __syncthreads();
#pragma unroll 8
    for (int k = 0; k < 64; ++k) {
      float a0 = As[ty * 2 + 0][k];
      float a1 = As[ty * 2 + 1][k];
      float4 w = *(float4*)&Ws[k][tx * 4];
      acc[0][0] += a0 * w.x; acc[0][1] += a0 * w.y; acc[0][2] += a0 * w.z; acc[0][3] += a0 * w.w;
      acc[1][0] += a1 * w.x; acc[1][1] += a1 * w.y; acc[1][2] += a1 * w.z; acc[1][3] += a1 * w.w;
    }
    __syncthreads();
  }
  float4 b4 = *(const float4*)&bias[tx * 4];
#pragma unroll
  for (int i = 0; i < 2; ++i) {
    int n = n0 + ty * 2 + i;
    if (n < N) {
      float4 o = make_float4(acc[i][0] + b4.x, acc[i][1] + b4.y,
                             acc[i][2] + b4.z, acc[i][3] + b4.w);
      *(float4*)&C[(size_t)n * 128 + tx * 4] = o;
    }
  }
}

// ---------------- orchestration ----------------

extern "C" void kernel_launch(void* const* d_in, const int* in_sizes, int n_in,
                              void* d_out, int out_size, void* d_ws, size_t ws_size,
                              hipStream_t stream) {
  const float* x   = (const float*)d_in[0];
  const int*   ei  = (const int*)d_in[1];
  const float* w1  = (const float*)d_in[2];
  const float* as1 = (const float*)d_in[3];
  const float* ad1 = (const float*)d_in[4];
  const float* b1  = (const float*)d_in[5];
  const float* w2  = (const float*)d_in[6];
  const float* as2 = (const float*)d_in[7];
  const float* ad2 = (const float*)d_in[8];
  const float* b2  = (const float*)d_in[9];
  const float* w3  = (const float*)d_in[10];
  const float* as3 = (const float*)d_in[11];
  const float* ad3 = (const float*)d_in[12];
  const float* b3  = (const float*)d_in[13];
  const float* rw1 = (const float*)d_in[14];
  const float* rb1 = (const float*)d_in[15];
  const float* rw2 = (const float*)d_in[16];
  const float* rb2 = (const float*)d_in[17];
  const float* lw  = (const float*)d_in[18];
  const float* lb  = (const float*)d_in[19];

  int N = in_sizes[0] / 4;
  int E = in_sizes[1] / 2;
  int ET = E + N;
  (void)ws_size;

  char* wsb = (char*)d_ws;
  size_t off = 0;
  auto alloc = [&](size_t bytes) -> void* {
    void* p = wsb + off;
    off += (bytes + 255) & ~(size_t)255;
    return p;
  };
  float* A    = (float*)alloc((size_t)N * 1024 * 4);  // transformed features h
  float* Bf   = (float*)alloc((size_t)N * 1024 * 4);  // GAT output
  float* P    = (float*)alloc((size_t)N * 128 * 4);   // projected features
  float* ssrc = (float*)alloc((size_t)N * 8 * 4);
  float* sdst = (float*)alloc((size_t)N * 8 * 4);
  float* elog = (float*)alloc((size_t)ET * 8 * 4);
  int* counts  = (int*)alloc((size_t)N * 4);
  int* offsets = (int*)alloc((size_t)(N + 1) * 4);
  int* cursor  = (int*)alloc((size_t)N * 4);
  int* pos_of  = (int*)alloc((size_t)ET * 4);
  int* srcs    = (int*)alloc((size_t)ET * 4);

  // CSR build (graph identical for all 3 layers)
  hipMemsetAsync(counts, 0, (size_t)N * 4, stream);
  hist_kernel<<<dim3((ET + THREADS - 1) / THREADS), dim3(THREADS), 0, stream>>>(ei, E, ET, counts);
  scan_kernel<<<dim3(1), dim3(1024), 0, stream>>>(counts, offsets, cursor, N);
  scatter_kernel<<<dim3((ET + THREADS - 1) / THREADS), dim3(THREADS), 0, stream>>>(ei, E, ET, cursor, pos_of, srcs);

  dim3 gEdgeH((ET * 8 + THREADS - 1) / THREADS);
  dim3 gNode(N);
  dim3 gGemm(16, (N + 63) / 64);
  dim3 gProj((N + 15) / 16);
  dim3 blk(THREADS);

  // ---- layer 1 ----
  feat1_kernel<<<dim3((N * 1024 + THREADS - 1) / THREADS), blk, 0, stream>>>(x, w1, A, N * 1024);
  scores_kernel<<<gNode, blk, 0, stream>>>(A, as1, ad1, ssrc, sdst, N);
  elog_kernel<<<gEdgeH, blk, 0, stream>>>(ei, E, ET, ssrc, sdst, pos_of, elog);
  agg_kernel<<<gNode, blk, 0, stream>>>(A, elog, offsets, srcs, b1, Bf, N);
  proj_kernel<<<gProj, blk, 0, stream>>>(Bf, rw1, rb1, P, N);

  // ---- layer 2 ----
  gemm128_kernel<<<gGemm, blk, 0, stream>>>(P, w2, A, N);
  scores_kernel<<<gNode, blk, 0, stream>>>(A, as2, ad2, ssrc, sdst, N);
  elog_kernel<<<gEdgeH, blk, 0, stream>>>(ei, E, ET, ssrc, sdst, pos_of, elog);
  agg_kernel<<<gNode, blk, 0, stream>>>(A, elog, offsets, srcs, b2, Bf, N);
  proj_kernel<<<gProj, blk, 0, stream>>>(Bf, rw2, rb2, P, N);

  // ---- layer 3 ----
  gemm128_kernel<<<gGemm, blk, 0, stream>>>(P, w3, A, N);
  scores_kernel<<<gNode, blk, 0, stream>>>(A, as3, ad3, ssrc, sdst, N);
  elog_kernel<<<gEdgeH, blk, 0, stream>>>(ei, E, ET, ssrc, sdst, pos_of, elog);
  agg_kernel<<<gNode, blk, 0, stream>>>(A, elog, offsets, srcs, b3, Bf, N);
  proj_kernel<<<gProj, blk, 0, stream>>>(Bf, lw, lb, (float*)d_out, N);
}

// Round 3
// 627.604 us; speedup vs baseline: 1.3733x; 1.2742x over previous
//
#include <hip/hip_runtime.h>
#include <hip/hip_fp16.h>
#include <math.h>

// GAT encoder: N=10000, E=160000 (+N self loops), H=8 heads, C=128, D=1024.
// CSR-by-dst built once; logits stored dst-sorted. Intermediates (h, gelu(h))
// stored fp16 to halve gather/stream traffic; all arithmetic fp32.

#define THREADS 256

struct __align__(8) Half4 { __half2 a, b; };

__device__ __forceinline__ float gelu_exact(float x) {
  return 0.5f * x * (1.0f + erff(x * 0.70710678118654752f));
}

__device__ __forceinline__ float4 h4_to_f4(float2 raw) {
  __half2 h01 = *(__half2*)&raw.x;
  __half2 h23 = *(__half2*)&raw.y;
  float2 f01 = __half22float2(h01);
  float2 f23 = __half22float2(h23);
  return make_float4(f01.x, f01.y, f23.x, f23.y);
}

// ---------------- CSR build ----------------

__global__ void hist_kernel(const int* __restrict__ ei, int E, int ET, int* __restrict__ counts) {
  int e = blockIdx.x * THREADS + threadIdx.x;
  if (e >= ET) return;
  int d = (e < E) ? ei[E + e] : (e - E);
  atomicAdd(&counts[d], 1);
}

__global__ __launch_bounds__(1024) void scan_kernel(const int* __restrict__ counts,
                                                    int* __restrict__ offsets,
                                                    int* __restrict__ cursor, int n) {
  __shared__ int sums[1024];
  int t = threadIdx.x;
  int per = (n + 1023) >> 10;
  int start = t * per; if (start > n) start = n;
  int end = start + per; if (end > n) end = n;
  int local = 0;
  for (int i = start; i < end; ++i) local += counts[i];
  sums[t] = local;
  __syncthreads();
  for (int off = 1; off < 1024; off <<= 1) {
    int add = (t >= off) ? sums[t - off] : 0;
    __syncthreads();
    sums[t] += add;
    __syncthreads();
  }
  int run = (t == 0) ? 0 : sums[t - 1];
  for (int i = start; i < end; ++i) {
    offsets[i] = run; cursor[i] = run; run += counts[i];
  }
  if (t == 1023) offsets[n] = run;
}

__global__ void scatter_kernel(const int* __restrict__ ei, int E, int ET,
                               int* __restrict__ cursor, int* __restrict__ pos_of,
                               int* __restrict__ srcs) {
  int e = blockIdx.x * THREADS + threadIdx.x;
  if (e >= ET) return;
  int s = (e < E) ? ei[e] : (e - E);
  int d = (e < E) ? ei[E + e] : (e - E);
  int pos = atomicAdd(&cursor[d], 1);
  pos_of[e] = pos;
  srcs[pos] = s;
}

// ---------------- layer 1 feature transform (K=4), fp16 out ----------------

__global__ void feat1_kernel(const float* __restrict__ x, const float* __restrict__ w,
                             __half* __restrict__ out, int total) {
  int idx = blockIdx.x * THREADS + threadIdx.x;
  if (idx >= total) return;
  int n = idx >> 10, d = idx & 1023;
  float4 xv = *(const float4*)&x[n * 4];
  float v = xv.x * w[d] + xv.y * w[1024 + d] + xv.z * w[2048 + d] + xv.w * w[3072 + d];
  out[idx] = __float2half_rn(v);
}

// ---------------- P[N,128] @ W[128,1024] -> A16[N,1024] fp16 ----------------
// 64x64 tile, K in 2 chunks of 64 (LDS 32KB -> 5 blocks/CU).

__global__ __launch_bounds__(256) void gemm128_kernel(const float* __restrict__ A,
                                                      const float* __restrict__ W,
                                                      __half* __restrict__ C, int N) {
  __shared__ float AsT[64][64];  // [k][row]
  __shared__ float Ws[64][64];   // [k][col]
  int t = threadIdx.x;
  int n0 = blockIdx.y * 64;
  int d0 = blockIdx.x * 64;
  int tx = t & 15, ty = t >> 4;
  float acc[4][4] = {};
  for (int kc = 0; kc < 128; kc += 64) {
    for (int i = t; i < 1024; i += 256) {
      int row = i >> 4;
      int col4 = (i & 15) << 2;
      int n = n0 + row;
      float4 v = make_float4(0.f, 0.f, 0.f, 0.f);
      if (n < N) v = *(const float4*)&A[(size_t)n * 128 + kc + col4];
      AsT[col4 + 0][row] = v.x; AsT[col4 + 1][row] = v.y;
      AsT[col4 + 2][row] = v.z; AsT[col4 + 3][row] = v.w;
    }
    for (int i = t; i < 1024; i += 256) {
      int k = i >> 4;
      int c4 = (i & 15) << 2;
      *(float4*)&Ws[k][c4] = *(const float4*)&W[(size_t)(kc + k) * 1024 + d0 + c4];
    }
    __syncthreads();
#pragma unroll 4
    for (int k = 0; k < 64; ++k) {
      float4 a = *(float4*)&AsT[k][ty * 4];
      float4 w = *(float4*)&Ws[k][tx * 4];
      acc[0][0] += a.x * w.x; acc[0][1] += a.x * w.y; acc[0][2] += a.x * w.z; acc[0][3] += a.x * w.w;
      acc[1][0] += a.y * w.x; acc[1][1] += a.y * w.y; acc[1][2] += a.y * w.z; acc[1][3] += a.y * w.w;
      acc[2][0] += a.z * w.x; acc[2][1] += a.z * w.y; acc[2][2] += a.z * w.z; acc[2][3] += a.z * w.w;
      acc[3][0] += a.w * w.x; acc[3][1] += a.w * w.y; acc[3][2] += a.w * w.z; acc[3][3] += a.w * w.w;
    }
    __syncthreads();
  }
#pragma unroll
  for (int i = 0; i < 4; ++i) {
    int n = n0 + ty * 4 + i;
    if (n < N) {
      Half4 p;
      p.a = __floats2half2_rn(acc[i][0], acc[i][1]);
      p.b = __floats2half2_rn(acc[i][2], acc[i][3]);
      *(Half4*)&C[(size_t)n * 1024 + d0 + tx * 4] = p;
    }
  }
}

// ---------------- per-node head scores (fp16 in) ----------------

__global__ __launch_bounds__(256) void scores_kernel(const __half* __restrict__ H16,
                                                     const float* __restrict__ as,
                                                     const float* __restrict__ ad,
                                                     float* __restrict__ ssrc,
                                                     float* __restrict__ sdst, int N) {
  int n = blockIdx.x;
  int t = threadIdx.x;
  int head = t >> 5, lane = t & 31;
  float4 h4 = h4_to_f4(*(const float2*)&H16[(size_t)n * 1024 + head * 128 + lane * 4]);
  float4 a4 = *(const float4*)&as[head * 128 + lane * 4];
  float4 d4 = *(const float4*)&ad[head * 128 + lane * 4];
  float s1 = h4.x * a4.x + h4.y * a4.y + h4.z * a4.z + h4.w * a4.w;
  float s2 = h4.x * d4.x + h4.y * d4.y + h4.z * d4.z + h4.w * d4.w;
  for (int off = 16; off; off >>= 1) {
    s1 += __shfl_down(s1, off, 32);
    s2 += __shfl_down(s2, off, 32);
  }
  if (lane == 0) { ssrc[n * 8 + head] = s1; sdst[n * 8 + head] = s2; }
}

// ---------------- per-edge logits, written in dst-sorted order ----------------

__global__ void elog_kernel(const int* __restrict__ ei, int E, int ET,
                            const float* __restrict__ ssrc, const float* __restrict__ sdst,
                            const int* __restrict__ pos_of, float* __restrict__ elog) {
  int i = blockIdx.x * THREADS + threadIdx.x;
  if (i >= ET * 8) return;
  int e = i >> 3, h = i & 7;
  int s = (e < E) ? ei[e] : (e - E);
  int d = (e < E) ? ei[E + e] : (e - E);
  float v = ssrc[s * 8 + h] + sdst[d * 8 + h];
  v = (v > 0.f) ? v : 0.2f * v;
  elog[(size_t)pos_of[e] * 8 + h] = v;
}

// ---------------- softmax + aggregation + bias + GELU (one block per dst) ----------------
// fp16 gather (2KB/row), fp32 math, fp16 gelu'd output.

__global__ __launch_bounds__(256) void agg_kernel(const __half* __restrict__ H16,
                                                  const float* __restrict__ elog,
                                                  const int* __restrict__ offsets,
                                                  const int* __restrict__ srcs,
                                                  const float* __restrict__ bias,
                                                  __half* __restrict__ G, int N) {
  int n = blockIdx.x;
  int t = threadIdx.x;
  int head = t >> 5, lane = t & 31;
  int start = offsets[n];
  int deg = offsets[n + 1] - start;
  __shared__ float sm[8], sz[8];
  __shared__ int ls[64];
  __shared__ float lal[64 * 8];

  // phase 1: online softmax stats per head
  float m = -1e30f, s = 0.f;
  for (int i = lane; i < deg; i += 32) {
    float v = elog[(size_t)(start + i) * 8 + head];
    if (v > m) { s = s * __expf(m - v) + 1.f; m = v; }
    else s += __expf(v - m);
  }
  for (int off = 16; off; off >>= 1) {
    float m2 = __shfl_down(m, off, 32);
    float s2 = __shfl_down(s, off, 32);
    float M = fmaxf(m, m2);
    s = s * __expf(m - M) + s2 * __expf(m2 - M);
    m = M;
  }
  if (lane == 0) { sm[head] = m; sz[head] = 1.f / s; }
  __syncthreads();

  int coff = t * 4;
  float4 acc = make_float4(0.f, 0.f, 0.f, 0.f);
  for (int c0 = 0; c0 < deg; c0 += 64) {
    int cm = min(64, deg - c0);
    if (t < cm) ls[t] = srcs[start + c0 + t];
    for (int j = t; j < cm * 8; j += 256) {
      int e = j >> 3, h = j & 7;
      lal[j] = __expf(elog[(size_t)(start + c0 + e) * 8 + h] - sm[h]);
    }
    __syncthreads();
    int i = 0;
    for (; i + 8 <= cm; i += 8) {
      float2 raw[8]; float av[8];
#pragma unroll
      for (int u = 0; u < 8; ++u) {
        raw[u] = *(const float2*)&H16[(size_t)ls[i + u] * 1024 + coff];
        av[u] = lal[(i + u) * 8 + head];
      }
#pragma unroll
      for (int u = 0; u < 8; ++u) {
        float4 f = h4_to_f4(raw[u]);
        acc.x += av[u] * f.x; acc.y += av[u] * f.y;
        acc.z += av[u] * f.z; acc.w += av[u] * f.w;
      }
    }
    for (; i < cm; ++i) {
      float a = lal[i * 8 + head];
      float4 f = h4_to_f4(*(const float2*)&H16[(size_t)ls[i] * 1024 + coff]);
      acc.x += a * f.x; acc.y += a * f.y; acc.z += a * f.z; acc.w += a * f.w;
    }
    __syncthreads();
  }
  float zinv = sz[head];
  float4 b4 = *(const float4*)&bias[coff];
  float o0 = gelu_exact(acc.x * zinv + b4.x);
  float o1 = gelu_exact(acc.y * zinv + b4.y);
  float o2 = gelu_exact(acc.z * zinv + b4.z);
  float o3 = gelu_exact(acc.w * zinv + b4.w);
  Half4 p;
  p.a = __floats2half2_rn(o0, o1);
  p.b = __floats2half2_rn(o2, o3);
  *(Half4*)&G[(size_t)n * 1024 + coff] = p;
}

// ---------------- G[N,1024] (fp16, already gelu'd) @ W[1024,128] + bias -> C[N,128] fp32 ----------------
// 16-row x 128-col tile, 32-k chunks. LDS 18KB.

__global__ __launch_bounds__(256) void proj_kernel(const __half* __restrict__ G,
                                                   const float* __restrict__ W,
                                                   const float* __restrict__ bias,
                                                   float* __restrict__ C, int N) {
  __shared__ float As[16][32];
  __shared__ float Ws[32][128];
  int t = threadIdx.x;
  int n0 = blockIdx.x * 16;
  int tx = t & 31, ty = t >> 5;
  float acc[2][4] = {};
  for (int kc = 0; kc < 1024; kc += 32) {
    {
      int row = t >> 4;        // 0..15
      int c2 = (t & 15) * 2;   // 0..30
      int n = n0 + row;
      float2 f = make_float2(0.f, 0.f);
      if (n < N) f = __half22float2(*(const __half2*)&G[(size_t)n * 1024 + kc + c2]);
      As[row][c2] = f.x; As[row][c2 + 1] = f.y;
    }
#pragma unroll
    for (int u = 0; u < 4; ++u) {
      int j = t + u * 256;
      int k = j >> 5, c4 = (j & 31) << 2;
      *(float4*)&Ws[k][c4] = *(const float4*)&W[(size_t)(kc + k) * 128 + c4];
    }
    __syncthreads();
#pragma unroll 8
    for (int k = 0; k < 32; ++k) {
      float a0 = As[ty * 2 + 0][k];
      float a1 = As[ty * 2 + 1][k];
      float4 w = *(float4*)&Ws[k][tx * 4];
      acc[0][0] += a0 * w.x; acc[0][1] += a0 * w.y; acc[0][2] += a0 * w.z; acc[0][3] += a0 * w.w;
      acc[1][0] += a1 * w.x; acc[1][1] += a1 * w.y; acc[1][2] += a1 * w.z; acc[1][3] += a1 * w.w;
    }
    __syncthreads();
  }
  float4 b4 = *(const float4*)&bias[tx * 4];
#pragma unroll
  for (int i = 0; i < 2; ++i) {
    int n = n0 + ty * 2 + i;
    if (n < N) {
      float4 o = make_float4(acc[i][0] + b4.x, acc[i][1] + b4.y,
                             acc[i][2] + b4.z, acc[i][3] + b4.w);
      *(float4*)&C[(size_t)n * 128 + tx * 4] = o;
    }
  }
}

// ---------------- orchestration ----------------

extern "C" void kernel_launch(void* const* d_in, const int* in_sizes, int n_in,
                              void* d_out, int out_size, void* d_ws, size_t ws_size,
                              hipStream_t stream) {
  const float* x   = (const float*)d_in[0];
  const int*   ei  = (const int*)d_in[1];
  const float* w1  = (const float*)d_in[2];
  const float* as1 = (const float*)d_in[3];
  const float* ad1 = (const float*)d_in[4];
  const float* b1  = (const float*)d_in[5];
  const float* w2  = (const float*)d_in[6];
  const float* as2 = (const float*)d_in[7];
  const float* ad2 = (const float*)d_in[8];
  const float* b2  = (const float*)d_in[9];
  const float* w3  = (const float*)d_in[10];
  const float* as3 = (const float*)d_in[11];
  const float* ad3 = (const float*)d_in[12];
  const float* b3  = (const float*)d_in[13];
  const float* rw1 = (const float*)d_in[14];
  const float* rb1 = (const float*)d_in[15];
  const float* rw2 = (const float*)d_in[16];
  const float* rb2 = (const float*)d_in[17];
  const float* lw  = (const float*)d_in[18];
  const float* lb  = (const float*)d_in[19];

  int N = in_sizes[0] / 4;
  int E = in_sizes[1] / 2;
  int ET = E + N;
  (void)ws_size;

  char* wsb = (char*)d_ws;
  size_t off = 0;
  auto alloc = [&](size_t bytes) -> void* {
    void* p = wsb + off;
    off += (bytes + 255) & ~(size_t)255;
    return p;
  };
  __half* A16 = (__half*)alloc((size_t)N * 1024 * 2);  // h (pre-attention features)
  __half* G   = (__half*)alloc((size_t)N * 1024 * 2);  // gelu(GAT output)
  float* P    = (float*)alloc((size_t)N * 128 * 4);    // projected features
  float* ssrc = (float*)alloc((size_t)N * 8 * 4);
  float* sdst = (float*)alloc((size_t)N * 8 * 4);
  float* elog = (float*)alloc((size_t)ET * 8 * 4);
  int* counts  = (int*)alloc((size_t)N * 4);
  int* offsets = (int*)alloc((size_t)(N + 1) * 4);
  int* cursor  = (int*)alloc((size_t)N * 4);
  int* pos_of  = (int*)alloc((size_t)ET * 4);
  int* srcs    = (int*)alloc((size_t)ET * 4);

  // CSR build (graph identical for all 3 layers)
  hipMemsetAsync(counts, 0, (size_t)N * 4, stream);
  hist_kernel<<<dim3((ET + THREADS - 1) / THREADS), dim3(THREADS), 0, stream>>>(ei, E, ET, counts);
  scan_kernel<<<dim3(1), dim3(1024), 0, stream>>>(counts, offsets, cursor, N);
  scatter_kernel<<<dim3((ET + THREADS - 1) / THREADS), dim3(THREADS), 0, stream>>>(ei, E, ET, cursor, pos_of, srcs);

  dim3 gEdgeH((ET * 8 + THREADS - 1) / THREADS);
  dim3 gNode(N);
  dim3 gGemm(16, (N + 63) / 64);
  dim3 gProj((N + 15) / 16);
  dim3 blk(THREADS);

  // ---- layer 1 ----
  feat1_kernel<<<dim3((N * 1024 + THREADS - 1) / THREADS), blk, 0, stream>>>(x, w1, A16, N * 1024);
  scores_kernel<<<gNode, blk, 0, stream>>>(A16, as1, ad1, ssrc, sdst, N);
  elog_kernel<<<gEdgeH, blk, 0, stream>>>(ei, E, ET, ssrc, sdst, pos_of, elog);
  agg_kernel<<<gNode, blk, 0, stream>>>(A16, elog, offsets, srcs, b1, G, N);
  proj_kernel<<<gProj, blk, 0, stream>>>(G, rw1, rb1, P, N);

  // ---- layer 2 ----
  gemm128_kernel<<<gGemm, blk, 0, stream>>>(P, w2, A16, N);
  scores_kernel<<<gNode, blk, 0, stream>>>(A16, as2, ad2, ssrc, sdst, N);
  elog_kernel<<<gEdgeH, blk, 0, stream>>>(ei, E, ET, ssrc, sdst, pos_of, elog);
  agg_kernel<<<gNode, blk, 0, stream>>>(A16, elog, offsets, srcs, b2, G, N);
  proj_kernel<<<gProj, blk, 0, stream>>>(G, rw2, rb2, P, N);

  // ---- layer 3 ----
  gemm128_kernel<<<gGemm, blk, 0, stream>>>(P, w3, A16, N);
  scores_kernel<<<gNode, blk, 0, stream>>>(A16, as3, ad3, ssrc, sdst, N);
  elog_kernel<<<gEdgeH, blk, 0, stream>>>(ei, E, ET, ssrc, sdst, pos_of, elog);
  agg_kernel<<<gNode, blk, 0, stream>>>(A16, elog, offsets, srcs, b3, G, N);
  proj_kernel<<<gProj, blk, 0, stream>>>(G, lw, lb, (float*)d_out, N);
}

// Round 4
// 523.988 us; speedup vs baseline: 1.6448x; 1.1977x over previous
//
#include <hip/hip_runtime.h>
#include <hip/hip_fp16.h>
#include <math.h>

// GAT encoder: N=10000, E=160000 (+N self loops), H=8 heads, C=128, D=1024.
// CSR-by-dst built once; logits dst-sorted. Intermediates fp16; dense GEMMs on
// matrix cores (mfma_f32_16x16x32_f16) with weights pre-transposed to fp16.

#define THREADS 256

typedef _Float16 f16x8 __attribute__((ext_vector_type(8)));
typedef float f32x4 __attribute__((ext_vector_type(4)));

struct __align__(8) Half4 { __half2 a, b; };

__device__ __forceinline__ float gelu_exact(float x) {
  return 0.5f * x * (1.0f + erff(x * 0.70710678118654752f));
}

__device__ __forceinline__ float4 h4_to_f4(float2 raw) {
  __half2 h01 = *(__half2*)&raw.x;
  __half2 h23 = *(__half2*)&raw.y;
  float2 f01 = __half22float2(h01);
  float2 f23 = __half22float2(h23);
  return make_float4(f01.x, f01.y, f23.x, f23.y);
}

// ---------------- CSR build ----------------

__global__ void hist_kernel(const int* __restrict__ ei, int E, int ET, int* __restrict__ counts) {
  int e = blockIdx.x * THREADS + threadIdx.x;
  if (e >= ET) return;
  int d = (e < E) ? ei[E + e] : (e - E);
  atomicAdd(&counts[d], 1);
}

__global__ __launch_bounds__(1024) void scan_kernel(const int* __restrict__ counts,
                                                    int* __restrict__ offsets,
                                                    int* __restrict__ cursor, int n) {
  __shared__ int sums[1024];
  int t = threadIdx.x;
  int per = (n + 1023) >> 10;
  int start = t * per; if (start > n) start = n;
  int end = start + per; if (end > n) end = n;
  int local = 0;
  for (int i = start; i < end; ++i) local += counts[i];
  sums[t] = local;
  __syncthreads();
  for (int off = 1; off < 1024; off <<= 1) {
    int add = (t >= off) ? sums[t - off] : 0;
    __syncthreads();
    sums[t] += add;
    __syncthreads();
  }
  int run = (t == 0) ? 0 : sums[t - 1];
  for (int i = start; i < end; ++i) {
    offsets[i] = run; cursor[i] = run; run += counts[i];
  }
  if (t == 1023) offsets[n] = run;
}

__global__ void scatter_kernel(const int* __restrict__ ei, int E, int ET,
                               int* __restrict__ cursor, int* __restrict__ pos_of,
                               int* __restrict__ srcs) {
  int e = blockIdx.x * THREADS + threadIdx.x;
  if (e >= ET) return;
  int s = (e < E) ? ei[e] : (e - E);
  int d = (e < E) ? ei[E + e] : (e - E);
  int pos = atomicAdd(&cursor[d], 1);
  pos_of[e] = pos;
  srcs[pos] = s;
}

// ---------------- weight transpose + fp16 convert: W[K][Ncol] -> Wt[Ncol][K] ----------------

__global__ void wconv_kernel(const float* __restrict__ in, __half* __restrict__ out,
                             int K, int Ncol, int total) {
  int idx = blockIdx.x * THREADS + threadIdx.x;
  if (idx >= total) return;
  int c = idx / K, k = idx - c * K;
  out[idx] = __float2half_rn(in[(size_t)k * Ncol + c]);
}

// ---------------- layer 1 feature transform (K=4), fp16 out ----------------

__global__ void feat1_kernel(const float* __restrict__ x, const float* __restrict__ w,
                             __half* __restrict__ out, int total) {
  int idx = blockIdx.x * THREADS + threadIdx.x;
  if (idx >= total) return;
  int n = idx >> 10, d = idx & 1023;
  float4 xv = *(const float4*)&x[n * 4];
  float v = xv.x * w[d] + xv.y * w[1024 + d] + xv.z * w[2048 + d] + xv.w * w[3072 + d];
  out[idx] = __float2half_rn(v);
}

// ---------------- MFMA GEMM: P16[N,128] @ W[128,1024] -> A16[N,1024] fp16 ----------------
// Wave computes a 16x16 output tile, K=128 in 4 MFMA steps. Wt2 is [1024][128] fp16.

__global__ __launch_bounds__(256) void gemm128_mfma(const __half* __restrict__ P16,
                                                    const __half* __restrict__ Wt,
                                                    __half* __restrict__ A16) {
  int wave = threadIdx.x >> 6, lane = threadIdx.x & 63;
  int r0 = blockIdx.y * 16;
  int c0 = blockIdx.x * 64 + wave * 16;
  int m = lane & 15, quad = lane >> 4;
  const __half* pa = P16 + (size_t)(r0 + m) * 128 + quad * 8;
  const __half* pb = Wt + (size_t)(c0 + m) * 128 + quad * 8;
  f32x4 acc = {0.f, 0.f, 0.f, 0.f};
#pragma unroll
  for (int k = 0; k < 128; k += 32) {
    f16x8 a = *(const f16x8*)(pa + k);
    f16x8 b = *(const f16x8*)(pb + k);
    acc = __builtin_amdgcn_mfma_f32_16x16x32_f16(a, b, acc, 0, 0, 0);
  }
#pragma unroll
  for (int i = 0; i < 4; ++i) {
    int row = quad * 4 + i;
    A16[(size_t)(r0 + row) * 1024 + c0 + m] = __float2half_rn(acc[i]);
  }
}

// ---------------- per-node head scores (fp16 in) ----------------

__global__ __launch_bounds__(256) void scores_kernel(const __half* __restrict__ H16,
                                                     const float* __restrict__ as,
                                                     const float* __restrict__ ad,
                                                     float* __restrict__ ssrc,
                                                     float* __restrict__ sdst, int N) {
  int n = blockIdx.x;
  int t = threadIdx.x;
  int head = t >> 5, lane = t & 31;
  float4 h4 = h4_to_f4(*(const float2*)&H16[(size_t)n * 1024 + head * 128 + lane * 4]);
  float4 a4 = *(const float4*)&as[head * 128 + lane * 4];
  float4 d4 = *(const float4*)&ad[head * 128 + lane * 4];
  float s1 = h4.x * a4.x + h4.y * a4.y + h4.z * a4.z + h4.w * a4.w;
  float s2 = h4.x * d4.x + h4.y * d4.y + h4.z * d4.z + h4.w * d4.w;
  for (int off = 16; off; off >>= 1) {
    s1 += __shfl_down(s1, off, 32);
    s2 += __shfl_down(s2, off, 32);
  }
  if (lane == 0) { ssrc[n * 8 + head] = s1; sdst[n * 8 + head] = s2; }
}

// ---------------- per-edge logits, written in dst-sorted order ----------------

__global__ void elog_kernel(const int* __restrict__ ei, int E, int ET,
                            const float* __restrict__ ssrc, const float* __restrict__ sdst,
                            const int* __restrict__ pos_of, float* __restrict__ elog) {
  int i = blockIdx.x * THREADS + threadIdx.x;
  if (i >= ET * 8) return;
  int e = i >> 3, h = i & 7;
  int s = (e < E) ? ei[e] : (e - E);
  int d = (e < E) ? ei[E + e] : (e - E);
  float v = ssrc[s * 8 + h] + sdst[d * 8 + h];
  v = (v > 0.f) ? v : 0.2f * v;
  elog[(size_t)pos_of[e] * 8 + h] = v;
}

// ---------------- softmax + aggregation + bias + GELU (one block per dst) ----------------

__global__ __launch_bounds__(256) void agg_kernel(const __half* __restrict__ H16,
                                                  const float* __restrict__ elog,
                                                  const int* __restrict__ offsets,
                                                  const int* __restrict__ srcs,
                                                  const float* __restrict__ bias,
                                                  __half* __restrict__ G, int N) {
  int n = blockIdx.x;
  int t = threadIdx.x;
  int head = t >> 5, lane = t & 31;
  int start = offsets[n];
  int deg = offsets[n + 1] - start;
  __shared__ float sm[8], sz[8];
  __shared__ int ls[64];
  __shared__ float lal[64 * 8];

  float m = -1e30f, s = 0.f;
  for (int i = lane; i < deg; i += 32) {
    float v = elog[(size_t)(start + i) * 8 + head];
    if (v > m) { s = s * __expf(m - v) + 1.f; m = v; }
    else s += __expf(v - m);
  }
  for (int off = 16; off; off >>= 1) {
    float m2 = __shfl_down(m, off, 32);
    float s2 = __shfl_down(s, off, 32);
    float M = fmaxf(m, m2);
    s = s * __expf(m - M) + s2 * __expf(m2 - M);
    m = M;
  }
  if (lane == 0) { sm[head] = m; sz[head] = 1.f / s; }
  __syncthreads();

  int coff = t * 4;
  float4 acc = make_float4(0.f, 0.f, 0.f, 0.f);
  for (int c0 = 0; c0 < deg; c0 += 64) {
    int cm = min(64, deg - c0);
    if (t < cm) ls[t] = srcs[start + c0 + t];
    for (int j = t; j < cm * 8; j += 256) {
      int e = j >> 3, h = j & 7;
      lal[j] = __expf(elog[(size_t)(start + c0 + e) * 8 + h] - sm[h]);
    }
    __syncthreads();
    int i = 0;
    for (; i + 8 <= cm; i += 8) {
      float2 raw[8]; float av[8];
#pragma unroll
      for (int u = 0; u < 8; ++u) {
        raw[u] = *(const float2*)&H16[(size_t)ls[i + u] * 1024 + coff];
        av[u] = lal[(i + u) * 8 + head];
      }
#pragma unroll
      for (int u = 0; u < 8; ++u) {
        float4 f = h4_to_f4(raw[u]);
        acc.x += av[u] * f.x; acc.y += av[u] * f.y;
        acc.z += av[u] * f.z; acc.w += av[u] * f.w;
      }
    }
    for (; i < cm; ++i) {
      float a = lal[i * 8 + head];
      float4 f = h4_to_f4(*(const float2*)&H16[(size_t)ls[i] * 1024 + coff]);
      acc.x += a * f.x; acc.y += a * f.y; acc.z += a * f.z; acc.w += a * f.w;
    }
    __syncthreads();
  }
  float zinv = sz[head];
  float4 b4 = *(const float4*)&bias[coff];
  float o0 = gelu_exact(acc.x * zinv + b4.x);
  float o1 = gelu_exact(acc.y * zinv + b4.y);
  float o2 = gelu_exact(acc.z * zinv + b4.z);
  float o3 = gelu_exact(acc.w * zinv + b4.w);
  Half4 p;
  p.a = __floats2half2_rn(o0, o1);
  p.b = __floats2half2_rn(o2, o3);
  *(Half4*)&G[(size_t)n * 1024 + coff] = p;
}

// ---------------- MFMA proj: G[N,1024] @ W[1024,128] + bias -> C[N,128] ----------------
// Wave computes a 16x16 output tile, K=1024 in 32 MFMA steps. Wt is [128][1024] fp16.

template <typename OutT>
__global__ __launch_bounds__(256) void proj_mfma(const __half* __restrict__ G,
                                                 const __half* __restrict__ Wt,
                                                 const float* __restrict__ bias,
                                                 OutT* __restrict__ C) {
  int wave = threadIdx.x >> 6, lane = threadIdx.x & 63;
  int r0 = blockIdx.y * 16;
  int c0 = blockIdx.x * 64 + wave * 16;
  int m = lane & 15, quad = lane >> 4;
  const __half* pa = G + (size_t)(r0 + m) * 1024 + quad * 8;
  const __half* pb = Wt + (size_t)(c0 + m) * 1024 + quad * 8;
  f32x4 acc = {0.f, 0.f, 0.f, 0.f};
#pragma unroll 8
  for (int k = 0; k < 1024; k += 32) {
    f16x8 a = *(const f16x8*)(pa + k);
    f16x8 b = *(const f16x8*)(pb + k);
    acc = __builtin_amdgcn_mfma_f32_16x16x32_f16(a, b, acc, 0, 0, 0);
  }
  float bv = bias[c0 + m];
#pragma unroll
  for (int i = 0; i < 4; ++i) {
    int row = quad * 4 + i;
    float v = acc[i] + bv;
    if constexpr (__is_same(OutT, __half)) {
      C[(size_t)(r0 + row) * 128 + c0 + m] = __float2half_rn(v);
    } else {
      C[(size_t)(r0 + row) * 128 + c0 + m] = v;
    }
  }
}

// ---------------- orchestration ----------------

extern "C" void kernel_launch(void* const* d_in, const int* in_sizes, int n_in,
                              void* d_out, int out_size, void* d_ws, size_t ws_size,
                              hipStream_t stream) {
  const float* x   = (const float*)d_in[0];
  const int*   ei  = (const int*)d_in[1];
  const float* w1  = (const float*)d_in[2];
  const float* as1 = (const float*)d_in[3];
  const float* ad1 = (const float*)d_in[4];
  const float* b1  = (const float*)d_in[5];
  const float* w2  = (const float*)d_in[6];
  const float* as2 = (const float*)d_in[7];
  const float* ad2 = (const float*)d_in[8];
  const float* b2  = (const float*)d_in[9];
  const float* w3  = (const float*)d_in[10];
  const float* as3 = (const float*)d_in[11];
  const float* ad3 = (const float*)d_in[12];
  const float* b3  = (const float*)d_in[13];
  const float* rw1 = (const float*)d_in[14];
  const float* rb1 = (const float*)d_in[15];
  const float* rw2 = (const float*)d_in[16];
  const float* rb2 = (const float*)d_in[17];
  const float* lw  = (const float*)d_in[18];
  const float* lb  = (const float*)d_in[19];

  int N = in_sizes[0] / 4;
  int E = in_sizes[1] / 2;
  int ET = E + N;
  (void)ws_size;

  char* wsb = (char*)d_ws;
  size_t off = 0;
  auto alloc = [&](size_t bytes) -> void* {
    void* p = wsb + off;
    off += (bytes + 255) & ~(size_t)255;
    return p;
  };
  __half* A16 = (__half*)alloc((size_t)N * 1024 * 2);  // h (pre-attention features)
  __half* G   = (__half*)alloc((size_t)N * 1024 * 2);  // gelu(GAT output)
  __half* P16 = (__half*)alloc((size_t)N * 128 * 2);   // projected features
  __half* wt2 = (__half*)alloc((size_t)1024 * 128 * 2);  // w2^T fp16 [1024][128]
  __half* wt3 = (__half*)alloc((size_t)1024 * 128 * 2);
  __half* rwt1 = (__half*)alloc((size_t)128 * 1024 * 2); // rw1^T fp16 [128][1024]
  __half* rwt2 = (__half*)alloc((size_t)128 * 1024 * 2);
  __half* lwt  = (__half*)alloc((size_t)128 * 1024 * 2);
  float* ssrc = (float*)alloc((size_t)N * 8 * 4);
  float* sdst = (float*)alloc((size_t)N * 8 * 4);
  float* elog = (float*)alloc((size_t)ET * 8 * 4);
  int* counts  = (int*)alloc((size_t)N * 4);
  int* offsets = (int*)alloc((size_t)(N + 1) * 4);
  int* cursor  = (int*)alloc((size_t)N * 4);
  int* pos_of  = (int*)alloc((size_t)ET * 4);
  int* srcs    = (int*)alloc((size_t)ET * 4);

  dim3 blk(THREADS);
  int WT = 128 * 1024;
  dim3 gW((WT + THREADS - 1) / THREADS);

  // CSR build + weight conversions (graph/weights identical for all layers)
  hipMemsetAsync(counts, 0, (size_t)N * 4, stream);
  hist_kernel<<<dim3((ET + THREADS - 1) / THREADS), blk, 0, stream>>>(ei, E, ET, counts);
  wconv_kernel<<<gW, blk, 0, stream>>>(w2, wt2, 128, 1024, WT);
  wconv_kernel<<<gW, blk, 0, stream>>>(w3, wt3, 128, 1024, WT);
  wconv_kernel<<<gW, blk, 0, stream>>>(rw1, rwt1, 1024, 128, WT);
  wconv_kernel<<<gW, blk, 0, stream>>>(rw2, rwt2, 1024, 128, WT);
  wconv_kernel<<<gW, blk, 0, stream>>>(lw, lwt, 1024, 128, WT);
  scan_kernel<<<dim3(1), dim3(1024), 0, stream>>>(counts, offsets, cursor, N);
  scatter_kernel<<<dim3((ET + THREADS - 1) / THREADS), blk, 0, stream>>>(ei, E, ET, cursor, pos_of, srcs);

  dim3 gEdgeH((ET * 8 + THREADS - 1) / THREADS);
  dim3 gNode(N);
  dim3 gGemm(16, N / 16);   // 64 cols per block (4 waves x 16), 16*64=1024 cols
  dim3 gProj(2, N / 16);    // 2*64=128 cols

  // ---- layer 1 ----
  feat1_kernel<<<dim3((N * 1024 + THREADS - 1) / THREADS), blk, 0, stream>>>(x, w1, A16, N * 1024);
  scores_kernel<<<gNode, blk, 0, stream>>>(A16, as1, ad1, ssrc, sdst, N);
  elog_kernel<<<gEdgeH, blk, 0, stream>>>(ei, E, ET, ssrc, sdst, pos_of, elog);
  agg_kernel<<<gNode, blk, 0, stream>>>(A16, elog, offsets, srcs, b1, G, N);
  proj_mfma<__half><<<gProj, blk, 0, stream>>>(G, rwt1, rb1, P16);

  // ---- layer 2 ----
  gemm128_mfma<<<gGemm, blk, 0, stream>>>(P16, wt2, A16);
  scores_kernel<<<gNode, blk, 0, stream>>>(A16, as2, ad2, ssrc, sdst, N);
  elog_kernel<<<gEdgeH, blk, 0, stream>>>(ei, E, ET, ssrc, sdst, pos_of, elog);
  agg_kernel<<<gNode, blk, 0, stream>>>(A16, elog, offsets, srcs, b2, G, N);
  proj_mfma<__half><<<gProj, blk, 0, stream>>>(G, rwt2, rb2, P16);

  // ---- layer 3 ----
  gemm128_mfma<<<gGemm, blk, 0, stream>>>(P16, wt3, A16);
  scores_kernel<<<gNode, blk, 0, stream>>>(A16, as3, ad3, ssrc, sdst, N);
  elog_kernel<<<gEdgeH, blk, 0, stream>>>(ei, E, ET, ssrc, sdst, pos_of, elog);
  agg_kernel<<<gNode, blk, 0, stream>>>(A16, elog, offsets, srcs, b3, G, N);
  proj_mfma<float><<<gProj, blk, 0, stream>>>(G, lwt, lb, (float*)d_out);
}